// Round 2
// baseline (176.448 us; speedup 1.0000x reference)
//
#include <hip/hip_runtime.h>

// SDF volume rendering (NeuS/VolSDF-style), float32 in/out.
//
// Per ray (96 samples):
//   alpha_i = 1 - exp(-beta * sigmoid(-sdf_i * beta))
//   t_i     = 1 - alpha_i + 1e-10
//   trans_i = exclusive cumprod of t ;  w_i = alpha_i * trans_i
//   depth   = sum w_i * z_i ;  rgb_c = sum w_i * rgb_{i,c}
//
// R6: R2-R5 all pinned at ~57us regardless of structure (scalar / LDS+float4
// / direct dwordx3), VALUBusy 13%, HBM 25% -> latency-bound on the per-block
// lifecycle: tiny blocks {issue 5 loads -> ~700cy wait -> ~700cy dependent
// shfl/exp chain -> die}, 8192 of them in ~6 residency generations, nothing
// overlaps a wave's own memory wait.
//
// Fix: software-pipeline 4 ray-pairs per wave with double-buffered registers
// (A/B, fully unrolled, static indexing only). Next pair's 5 loads are issued
// BEFORE the current pair's compute (sched_barrier(0) fences each load pack),
// so the dependent shfl/exp chain of ray-set k runs with ray-set k+1's loads
// in flight. Grid 8192 -> 2048 blocks amortizes launch/drain 4x.
// 32-bit offsets (max idx 18.9M) keep address VGPRs at 1 each.
//
// Block = 256 threads = 8 rays/pass * 4 passes = 32 rays/block, zero LDS.

#define SDFR_NS 96
#define SDFR_RPP 8    // rays per pass per block (256 thr / 32 lanes)
#define SDFR_PASSES 4
#define SDFR_RPB (SDFR_RPP * SDFR_PASSES)  // 32 rays per block

struct f3 { float x, y, z; };   // 12B -> global_load_dwordx3

__device__ __forceinline__ void render_ray(
    int ray, int l, float beta,
    const f3& sv, const f3& zv, const f3& ca, const f3& cb, const f3& cc,
    int sb,
    float* __restrict__ out_depth, float* __restrict__ out_rgb,
    float* __restrict__ out_sdf,   float* __restrict__ out_z)
{
    // passthrough stores (bit-exact, straight from the loaded registers)
    *(f3*)(out_sdf + sb) = sv;
    *(f3*)(out_z   + sb) = zv;

    // sigmoid(-s*beta) = 1/(1+exp(s*beta)); e = exp(-beta*sig)
    const float e0 = __expf(-beta * __builtin_amdgcn_rcpf(1.0f + __expf(sv.x * beta)));
    const float e1 = __expf(-beta * __builtin_amdgcn_rcpf(1.0f + __expf(sv.y * beta)));
    const float e2 = __expf(-beta * __builtin_amdgcn_rcpf(1.0f + __expf(sv.z * beta)));
    const float a0 = 1.0f - e0, t0 = e0 + 1e-10f;
    const float a1 = 1.0f - e1, t1 = e1 + 1e-10f;
    const float a2 = 1.0f - e2, t2 = e2 + 1e-10f;

    // 32-lane exclusive prefix product of per-lane local product
    const float m = t0 * t1 * t2;
    float scan = m;
    #pragma unroll
    for (int d = 1; d < 32; d <<= 1) {
        float v = __shfl_up(scan, d, 32);
        if (l >= d) scan *= v;
    }
    float E = __shfl_up(scan, 1, 32);
    if (l == 0) E = 1.0f;

    const float w0 = a0 * E;
    const float w1 = a1 * E * t0;
    const float w2 = a2 * E * t0 * t1;

    float depth = w0 * zv.x + w1 * zv.y + w2 * zv.z;
    float r0    = w0 * ca.x + w1 * cb.x + w2 * cc.x;
    float r1    = w0 * ca.y + w1 * cb.y + w2 * cc.y;
    float r2    = w0 * ca.z + w1 * cb.z + w2 * cc.z;

    #pragma unroll
    for (int d = 16; d >= 1; d >>= 1) {
        depth += __shfl_xor(depth, d, 32);
        r0    += __shfl_xor(r0, d, 32);
        r1    += __shfl_xor(r1, d, 32);
        r2    += __shfl_xor(r2, d, 32);
    }

    if (l == 0) {
        out_depth[ray] = depth;
        f3 o; o.x = r0; o.y = r1; o.z = r2;
        *(f3*)(out_rgb + ray * 3) = o;
    }
}

__global__ __launch_bounds__(256, 8) void sdf_render_kernel(
    const float* __restrict__ rgb,      // [N*96*3]
    const float* __restrict__ sdf,      // [N*96]
    const float* __restrict__ z_vals,   // [N*96]
    const int*   __restrict__ beta_p,   // scalar (int32, or f32 bit pattern)
    float* __restrict__ out_depth,      // [N]
    float* __restrict__ out_rgb,        // [N,3]
    float* __restrict__ out_sdf,        // [N*96]
    float* __restrict__ out_z,          // [N*96]
    int n_rays)
{
    const int t = threadIdx.x;
    const int g = t >> 5;        // ray group within pass
    const int l = t & 31;        // lane l owns samples [3l, 3l+3)

    // beta decode: small int is the value; huge magnitude is an f32 pattern
    int bi = *beta_p;
    float beta;
    if (bi > 1000000 || bi < -1000000) {
        union { int i; float f; } u; u.i = bi; beta = u.f;
    } else {
        beta = (float)bi;
    }

    const int rA0 = blockIdx.x * SDFR_RPB + 0 * SDFR_RPP + g;
    const int rB0 = blockIdx.x * SDFR_RPB + 1 * SDFR_RPP + g;
    const int rA1 = blockIdx.x * SDFR_RPB + 2 * SDFR_RPP + g;
    const int rB1 = blockIdx.x * SDFR_RPB + 3 * SDFR_RPP + g;

    f3 svA, zvA, caA, cbA, ccA; int sbA;
    f3 svB, zvB, caB, cbB, ccB; int sbB;

#define SDFR_LOAD(SFX, RAY)                                         \
    do {                                                            \
        sb##SFX = (RAY) * SDFR_NS + 3 * l;                          \
        const int rb_ = (RAY) * (SDFR_NS * 3) + 9 * l;              \
        sv##SFX = *(const f3*)(sdf    + sb##SFX);                   \
        zv##SFX = *(const f3*)(z_vals + sb##SFX);                   \
        ca##SFX = *(const f3*)(rgb + rb_ + 0);                      \
        cb##SFX = *(const f3*)(rgb + rb_ + 3);                      \
        cc##SFX = *(const f3*)(rgb + rb_ + 6);                      \
    } while (0)

#define SDFR_RUN(SFX, RAY)                                          \
    render_ray((RAY), l, beta, sv##SFX, zv##SFX, ca##SFX, cb##SFX,  \
               cc##SFX, sb##SFX, out_depth, out_rgb, out_sdf, out_z)

    const bool vA0 = (rA0 < n_rays);
    const bool vB0 = (rB0 < n_rays);
    const bool vA1 = (rA1 < n_rays);
    const bool vB1 = (rB1 < n_rays);

    if (vA0) SDFR_LOAD(A, rA0);
    if (vB0) SDFR_LOAD(B, rB0);
    __builtin_amdgcn_sched_barrier(0);   // both packs issued before any compute

    if (vA0) SDFR_RUN(A, rA0);           // compute A0 with B0(+A1) in flight
    if (vA1) SDFR_LOAD(A, rA1);
    __builtin_amdgcn_sched_barrier(0);

    if (vB0) SDFR_RUN(B, rB0);           // compute B0 with A1(+B1) in flight
    if (vB1) SDFR_LOAD(B, rB1);
    __builtin_amdgcn_sched_barrier(0);

    if (vA1) SDFR_RUN(A, rA1);           // compute A1 with B1 in flight
    if (vB1) SDFR_RUN(B, rB1);

#undef SDFR_LOAD
#undef SDFR_RUN
}

extern "C" void kernel_launch(void* const* d_in, const int* in_sizes, int n_in,
                              void* d_out, int out_size, void* d_ws, size_t ws_size,
                              hipStream_t stream) {
    (void)n_in; (void)d_ws; (void)ws_size; (void)out_size;

    const float* rgb    = (const float*)d_in[0];
    const float* sdf    = (const float*)d_in[1];
    const float* z      = (const float*)d_in[2];
    const int*   beta_p = (const int*)d_in[3];

    const int n_rays = in_sizes[1] / SDFR_NS;  // 65536

    // output layout (f32): depth[N] | rgb[N*3] | sdf[N*96] | z[N*96]
    float* out_depth = (float*)d_out;
    float* out_rgb   = out_depth + n_rays;
    float* out_sdf   = out_rgb   + (size_t)n_rays * 3;
    float* out_z     = out_sdf   + (size_t)n_rays * SDFR_NS;

    const int grid = (n_rays + SDFR_RPB - 1) / SDFR_RPB;  // 2048
    sdf_render_kernel<<<grid, 256, 0, stream>>>(
        rgb, sdf, z, beta_p, out_depth, out_rgb, out_sdf, out_z, n_rays);
}

// Round 5
// 164.736 us; speedup vs baseline: 1.0711x; 1.0711x over previous
//
#include <hip/hip_runtime.h>

// SDF volume rendering (NeuS/VolSDF-style), float32 in/out.
//
// Per ray (96 samples):
//   alpha_i = 1 - exp(-beta * sigmoid(-sdf_i * beta))
//   t_i     = 1 - alpha_i + 1e-10
//   trans_i = exclusive cumprod of t ;  w_i = alpha_i * trans_i
//   depth   = sum w_i * z_i ;  rgb_c = sum w_i * rgb_{i,c}
//
// R9 == R7 with compile fix: __builtin_nontemporal_store rejects HIP's
// float4 (HIP_vector_type class). Use a native clang ext_vector_type(4)
// instead -- same global_store_dwordx4, with the nt cache bit.
//
// R7 theory: R2-R6 all pinned at 56-63us across totally different load
// structures (scalar / LDS+float4 / dwordx3 / SW-pipelined). The invariant:
// every version issues the 50MB passthrough stores MID-KERNEL and then
// recycles registers (VGPR_Count 16-28). A VMEM store reads its source VGPRs
// asynchronously; overwriting them forces s_waitcnt on STORE retirement,
// which under a congested write path is thousands of cycles. Every compute
// wave was serializing on store drain -> VALUBusy 13%, HBM 25%, invariant.
//
// Fix: role-split. Blocks [0,2048) are pure grid-stride float4 copy
// (sdf,z -> out_sdf,out_z) -- the exact 6.3 TB/s ubench pattern, with
// nontemporal stores so the write stream doesn't evict inputs from L3.
// Blocks [2048, 2048+8192) are R5's compute structure with the passthrough
// stores REMOVED: their only stores are 16B/ray at wave end, no
// register-reuse-after-store hazard. sdf/z re-read by compute is L3-hot.

#define SDFR_NS 96
#define SDFR_NCOPY 2048   // copy blocks (dispatched first)

struct f3 { float x, y, z; };                              // 12B -> dwordx3
typedef float fv4 __attribute__((ext_vector_type(4)));     // true vector type

__global__ __launch_bounds__(256, 8) void sdf_render_kernel(
    const float* __restrict__ rgb,      // [N*96*3]
    const float* __restrict__ sdf,      // [N*96]
    const float* __restrict__ z_vals,   // [N*96]
    const int*   __restrict__ beta_p,   // scalar (int32, or f32 bit pattern)
    float* __restrict__ out_depth,      // [N]
    float* __restrict__ out_rgb,        // [N,3]
    float* __restrict__ out_sdf,        // [N*96]
    float* __restrict__ out_z,          // [N*96]
    int n_rays)
{
    const int t = threadIdx.x;

    if (blockIdx.x < SDFR_NCOPY) {
        // ---------------- copy role: pure float4 stream ----------------
        // n4 = floats per array / 4 ; N=65536 -> 1,572,864 f4 per array,
        // exactly 3 per copy thread per array.
        const int n4 = (n_rays * SDFR_NS) / 4;
        const int stride = SDFR_NCOPY * 256;
        const fv4* __restrict__ s4 = (const fv4*)sdf;
        const fv4* __restrict__ z4 = (const fv4*)z_vals;
        fv4* __restrict__ os4 = (fv4*)out_sdf;
        fv4* __restrict__ oz4 = (fv4*)out_z;

        for (int i = blockIdx.x * 256 + t; i < n4; i += stride) {
            const fv4 a = s4[i];
            const fv4 b = z4[i];
            __builtin_nontemporal_store(a, os4 + i);
            __builtin_nontemporal_store(b, oz4 + i);
        }
        return;
    }

    // ---------------- compute role: 32 lanes per ray ----------------
    const int cbid = blockIdx.x - SDFR_NCOPY;
    const int tid  = cbid * 256 + t;
    const int ray  = tid >> 5;        // 2 rays per wave
    const int l    = tid & 31;        // lane l owns samples [3l, 3l+3)
    if (ray >= n_rays) return;

    const int sb = ray * SDFR_NS + 3 * l;        // sdf/z float index
    const int rb = ray * (SDFR_NS * 3) + 9 * l;  // rgb float index

    // 5 independent, branch-free, coalesced wide loads
    const f3 sv = *(const f3*)(sdf    + sb);
    const f3 zv = *(const f3*)(z_vals + sb);
    const f3 ca = *(const f3*)(rgb + rb + 0);
    const f3 cb = *(const f3*)(rgb + rb + 3);
    const f3 cc = *(const f3*)(rgb + rb + 6);
    __builtin_amdgcn_sched_barrier(0);  // pin all loads above any consumer

    // beta decode: small int is the value; huge magnitude is an f32 pattern
    int bi = *beta_p;
    float beta;
    if (bi > 1000000 || bi < -1000000) {
        union { int i; float f; } u; u.i = bi; beta = u.f;
    } else {
        beta = (float)bi;
    }

    // sigmoid(-s*beta) = 1/(1+exp(s*beta)); e = exp(-beta*sig)
    const float e0 = __expf(-beta * __builtin_amdgcn_rcpf(1.0f + __expf(sv.x * beta)));
    const float e1 = __expf(-beta * __builtin_amdgcn_rcpf(1.0f + __expf(sv.y * beta)));
    const float e2 = __expf(-beta * __builtin_amdgcn_rcpf(1.0f + __expf(sv.z * beta)));
    const float a0 = 1.0f - e0, t0 = e0 + 1e-10f;
    const float a1 = 1.0f - e1, t1 = e1 + 1e-10f;
    const float a2 = 1.0f - e2, t2 = e2 + 1e-10f;

    // 32-lane exclusive prefix product of per-lane local product
    const float m = t0 * t1 * t2;
    float scan = m;
    #pragma unroll
    for (int d = 1; d < 32; d <<= 1) {
        float v = __shfl_up(scan, d, 32);
        if (l >= d) scan *= v;
    }
    float E = __shfl_up(scan, 1, 32);
    if (l == 0) E = 1.0f;

    const float w0 = a0 * E;
    const float w1 = a1 * E * t0;
    const float w2 = a2 * E * t0 * t1;

    float depth = w0 * zv.x + w1 * zv.y + w2 * zv.z;
    float r0    = w0 * ca.x + w1 * cb.x + w2 * cc.x;
    float r1    = w0 * ca.y + w1 * cb.y + w2 * cc.y;
    float r2    = w0 * ca.z + w1 * cb.z + w2 * cc.z;

    #pragma unroll
    for (int d = 16; d >= 1; d >>= 1) {
        depth += __shfl_xor(depth, d, 32);
        r0    += __shfl_xor(r0, d, 32);
        r1    += __shfl_xor(r1, d, 32);
        r2    += __shfl_xor(r2, d, 32);
    }

    // only stores in the compute role: 16B per ray, at wave end
    if (l == 0) {
        out_depth[ray] = depth;
        f3 o; o.x = r0; o.y = r1; o.z = r2;
        *(f3*)(out_rgb + ray * 3) = o;
    }
}

extern "C" void kernel_launch(void* const* d_in, const int* in_sizes, int n_in,
                              void* d_out, int out_size, void* d_ws, size_t ws_size,
                              hipStream_t stream) {
    (void)n_in; (void)d_ws; (void)ws_size; (void)out_size;

    const float* rgb    = (const float*)d_in[0];
    const float* sdf    = (const float*)d_in[1];
    const float* z      = (const float*)d_in[2];
    const int*   beta_p = (const int*)d_in[3];

    const int n_rays = in_sizes[1] / SDFR_NS;  // 65536

    // output layout (f32): depth[N] | rgb[N*3] | sdf[N*96] | z[N*96]
    float* out_depth = (float*)d_out;
    float* out_rgb   = out_depth + n_rays;
    float* out_sdf   = out_rgb   + (size_t)n_rays * 3;
    float* out_z     = out_sdf   + (size_t)n_rays * SDFR_NS;

    // copy blocks first, then 32-lanes-per-ray compute blocks
    const int comp_blocks = (n_rays * 32 + 255) / 256;   // 8192
    const int grid = SDFR_NCOPY + comp_blocks;           // 10240
    sdf_render_kernel<<<grid, 256, 0, stream>>>(
        rgb, sdf, z, beta_p, out_depth, out_rgb, out_sdf, out_z, n_rays);
}